// Round 1
// baseline (427.237 us; speedup 1.0000x reference)
//
#include <hip/hip_runtime.h>
#include <math.h>

#define D 128
#define CAP 64
#define NEG 0.2f
#define LAMB 0.1f

__device__ inline float waveReduceSum(float v) {
    #pragma unroll
    for (int m = 32; m; m >>= 1) v += __shfl_xor(v, m);
    return v;
}
__device__ inline float waveReduceMax(float v) {
    #pragma unroll
    for (int m = 32; m; m >>= 1) v = fmaxf(v, __shfl_xor(v, m));
    return v;
}
// block of 128 threads = 2 waves
__device__ inline float blockReduceSum128(float v, float* lds) {
    v = waveReduceSum(v);
    int w = threadIdx.x >> 6;
    if ((threadIdx.x & 63) == 0) lds[w] = v;
    __syncthreads();
    float r = lds[0] + lds[1];
    __syncthreads();
    return r;
}

// xw = x @ W_gcn ; also xr_rel = x.Wrel, xroot = x.Wroot (per node scalars)
__global__ __launch_bounds__(128) void k_gemm(
    const float* __restrict__ x, const float* __restrict__ W,
    const float* __restrict__ Wrel, const float* __restrict__ Wroot,
    float* __restrict__ xw, float* __restrict__ xr_rel,
    float* __restrict__ xroot, int n) {
    __shared__ float xs[16][D];
    __shared__ float red[2];
    const int nb = blockIdx.x * 16;
    const int tid = threadIdx.x;
    #pragma unroll
    for (int k = 0; k < 16; k++) {
        int i = nb + k;
        xs[k][tid] = (i < n) ? x[(size_t)i * D + tid] : 0.f;
    }
    __syncthreads();
    float acc[16];
    #pragma unroll
    for (int k = 0; k < 16; k++) acc[k] = 0.f;
    #pragma unroll 4
    for (int d = 0; d < D; d++) {
        float w = W[d * D + tid];
        #pragma unroll
        for (int k = 0; k < 16; k++) acc[k] += xs[k][d] * w;
    }
    #pragma unroll
    for (int k = 0; k < 16; k++) {
        int i = nb + k;
        if (i < n) xw[(size_t)i * D + tid] = acc[k];
    }
    // fused per-node scalar dots
    float wr = Wrel[tid], wo = Wroot[tid];
    for (int k = 0; k < 16; k++) {
        int i = nb + k;
        float sr = blockReduceSum128(xs[k][tid] * wr, red);
        float so = blockReduceSum128(xs[k][tid] * wo, red);
        if (i < n && tid == 0) { xr_rel[i] = sr; xroot[i] = so; }
    }
}

// bucketed adjacency build + scalar agg scatter
__global__ void k_edges(const int* __restrict__ ei, int etot,
                        int* __restrict__ cnt_col, int* __restrict__ cnt_row,
                        int* __restrict__ lst_col, int* __restrict__ lst_row,
                        float* __restrict__ agg_s,
                        const float* __restrict__ xr_rel) {
    int e = blockIdx.x * blockDim.x + threadIdx.x;
    if (e >= etot) return;
    int r = ei[e];
    int c = ei[etot + e];
    int s1 = atomicAdd(&cnt_col[c], 1);
    if (s1 < CAP) lst_col[(size_t)c * CAP + s1] = e;
    int s2 = atomicAdd(&cnt_row[r], 1);
    if (s2 < CAP) lst_row[(size_t)r * CAP + s2] = e;
    atomicAdd(&agg_s[c], xr_rel[r]);
}

__global__ void k_dinv(const int* __restrict__ cnt_col,
                       float* __restrict__ dinv, int n) {
    int i = blockIdx.x * blockDim.x + threadIdx.x;
    if (i < n) {
        float d = (float)cnt_col[i];
        dinv[i] = (d > 0.f) ? rsqrtf(d) : 0.f;
    }
}

// x_transform per col-node + fused lk/lq scalars
__global__ __launch_bounds__(128) void k_xt(
    const float* __restrict__ xw, const int* __restrict__ ei,
    const int* __restrict__ cnt_col, const int* __restrict__ lst_col,
    const float* __restrict__ dinv, const float* __restrict__ b_gcn,
    const float* __restrict__ Wkey, const float* __restrict__ bkey,
    const float* __restrict__ Wq, const float* __restrict__ bq,
    float* __restrict__ xt, float* __restrict__ lk, float* __restrict__ lq,
    int n, int etot) {
    const int c = blockIdx.x;
    const int tid = threadIdx.x;
    __shared__ int rs[CAP];
    __shared__ float ns[CAP];
    __shared__ float red[2];
    int deg = min(cnt_col[c], CAP);
    float dc = dinv[c];
    if (tid < deg) {
        int e = lst_col[(size_t)c * CAP + tid];
        int rr = ei[e];
        rs[tid] = rr;
        ns[tid] = dinv[rr] * dc;
    }
    __syncthreads();
    float acc = b_gcn[tid];
    for (int k = 0; k < deg; k++)
        acc += ns[k] * xw[(size_t)rs[k] * D + tid];
    xt[(size_t)c * D + tid] = acc;
    float sk = blockReduceSum128(acc * Wkey[tid], red);
    float sq = blockReduceSum128(acc * Wq[tid], red);
    if (tid == 0) {
        float vk = sk + bkey[0];
        float vq = sq + bq[0];
        lk[c] = vk > 0.f ? vk : NEG * vk;
        lq[c] = vq > 0.f ? vq : NEG * vq;
    }
}

// per row-node: dual softmax + in-register reweight + KE / sum-QE -> score_sum
__global__ __launch_bounds__(128) void k_fused(
    const float* __restrict__ xt, const int* __restrict__ ei,
    const int* __restrict__ cnt_row, const int* __restrict__ lst_row,
    const float* __restrict__ lk, const float* __restrict__ lq,
    float* __restrict__ score_sum, int n, int etot, int eorig) {
    const int r = blockIdx.x;
    const int tid = threadIdx.x;
    __shared__ int cs[CAP];
    __shared__ unsigned char realf[CAP];
    __shared__ float al[CAP], be[CAP];
    __shared__ float red[2];
    __shared__ int nrealsh;
    int deg = min(cnt_row[r], CAP);
    if (tid < deg) {
        int e = lst_row[(size_t)r * CAP + tid];
        int c = ei[etot + e];
        cs[tid] = c;
        realf[tid] = (e < eorig) ? 1 : 0;
        al[tid] = lk[c];   // raw scores for now
        be[tid] = lq[c];
    }
    __syncthreads();
    if (tid < 64) {  // wave 0 handles the softmax over <=64 edges
        float vk = (tid < deg) ? al[tid] : -3.4e38f;
        float vq = (tid < deg) ? be[tid] : -3.4e38f;
        float mk = waveReduceMax(vk);
        float mq = waveReduceMax(vq);
        float ek = (tid < deg) ? __expf(al[tid] - mk) : 0.f;
        float eq = (tid < deg) ? __expf(be[tid] - mq) : 0.f;
        float zk = waveReduceSum(ek);
        float zq = waveReduceSum(eq);
        if (tid < deg) { al[tid] = ek / zk; be[tid] = eq / zq; }
        int isreal = (tid < deg) ? (int)realf[tid] : 0;
        unsigned long long b = __ballot(isreal);
        if (tid == 0) nrealsh = __popcll(b);
    }
    __syncthreads();
    float xrk = 0.f, xrq = 0.f;
    for (int k = 0; k < deg; k++) {
        float v = xt[(size_t)cs[k] * D + tid];
        xrk += al[k] * v;
        xrq += be[k] * v;
    }
    float xtr = xt[(size_t)r * D + tid];
    float KE = blockReduceSum128(fabsf(xrk - xtr), red);
    float sp = 0.f;
    for (int k = 0; k < deg; k++) {
        if (realf[k])  // uniform branch
            sp += fabsf(xrq - xt[(size_t)cs[k] * D + tid]);
    }
    float SQE = blockReduceSum128(sp, red);
    if (tid == 0) score_sum[r] = (float)nrealsh * KE - SQE;
}

__global__ void k_out(const float* __restrict__ agg_s,
                      const float* __restrict__ xroot,
                      const float* __restrict__ brel,
                      const float* __restrict__ score_sum,
                      float* __restrict__ out, int n) {
    int i = blockIdx.x * blockDim.x + threadIdx.x;
    if (i >= n) return;
    float z = agg_s[i] + brel[0] + xroot[i];
    float f = 1.f / (1.f + __expf(-z));
    out[i] = f - LAMB * score_sum[i];
}

extern "C" void kernel_launch(void* const* d_in, const int* in_sizes, int n_in,
                              void* d_out, int out_size, void* d_ws, size_t ws_size,
                              hipStream_t stream) {
    const float* x    = (const float*)d_in[0];
    const int*   ei   = (const int*)d_in[1];
    const float* Wg   = (const float*)d_in[2];
    const float* bg   = (const float*)d_in[3];
    const float* Wk   = (const float*)d_in[4];
    const float* bk   = (const float*)d_in[5];
    const float* Wq   = (const float*)d_in[6];
    const float* bq   = (const float*)d_in[7];
    const float* Wr   = (const float*)d_in[8];
    const float* br   = (const float*)d_in[9];
    const float* Wo   = (const float*)d_in[10];

    const int n = in_sizes[0] / D;        // 50000
    const int etot = in_sizes[1] / 2;     // 850000
    const int eorig = etot - n;           // 800000

    char* ws = (char*)d_ws;
    size_t off = 0;
    auto alloc = [&](size_t bytes) -> void* {
        void* p = ws + off;
        off += (bytes + 255) & ~(size_t)255;
        return p;
    };
    float* xw      = (float*)alloc((size_t)n * D * 4);
    float* xt      = (float*)alloc((size_t)n * D * 4);
    int*   lst_col = (int*)alloc((size_t)n * CAP * 4);
    int*   lst_row = (int*)alloc((size_t)n * CAP * 4);
    int*   cnt_col = (int*)alloc((size_t)n * 4);
    int*   cnt_row = (int*)alloc((size_t)n * 4);
    float* agg_s   = (float*)alloc((size_t)n * 4);
    float* dinv    = (float*)alloc((size_t)n * 4);
    float* lkv     = (float*)alloc((size_t)n * 4);
    float* lqv     = (float*)alloc((size_t)n * 4);
    float* xr_rel  = (float*)alloc((size_t)n * 4);
    float* xroot   = (float*)alloc((size_t)n * 4);
    float* ssum    = (float*)alloc((size_t)n * 4);

    hipMemsetAsync(cnt_col, 0, (size_t)n * 4, stream);
    hipMemsetAsync(cnt_row, 0, (size_t)n * 4, stream);
    hipMemsetAsync(agg_s, 0, (size_t)n * 4, stream);

    k_gemm<<<(n + 15) / 16, 128, 0, stream>>>(x, Wg, Wr, Wo, xw, xr_rel, xroot, n);
    k_edges<<<(etot + 255) / 256, 256, 0, stream>>>(ei, etot, cnt_col, cnt_row,
                                                    lst_col, lst_row, agg_s, xr_rel);
    k_dinv<<<(n + 255) / 256, 256, 0, stream>>>(cnt_col, dinv, n);
    k_xt<<<n, 128, 0, stream>>>(xw, ei, cnt_col, lst_col, dinv, bg, Wk, bk,
                                Wq, bq, xt, lkv, lqv, n, etot);
    k_fused<<<n, 128, 0, stream>>>(xt, ei, cnt_row, lst_row, lkv, lqv, ssum,
                                   n, etot, eorig);
    k_out<<<(n + 255) / 256, 256, 0, stream>>>(agg_s, xroot, br, ssum,
                                               (float*)d_out, n);
}

// Round 2
// 341.391 us; speedup vs baseline: 1.2515x; 1.2515x over previous
//
#include <hip/hip_runtime.h>
#include <math.h>

#define D 128
#define CAP 64
#define NEG 0.2f
#define LAMB 0.1f

__device__ inline float waveReduceSum(float v) {
    #pragma unroll
    for (int m = 32; m; m >>= 1) v += __shfl_xor(v, m);
    return v;
}
__device__ inline float waveReduceMax(float v) {
    #pragma unroll
    for (int m = 32; m; m >>= 1) v = fmaxf(v, __shfl_xor(v, m));
    return v;
}
// block of 128 threads = 2 waves
__device__ inline float blockReduceSum128(float v, float* lds) {
    v = waveReduceSum(v);
    int w = threadIdx.x >> 6;
    if ((threadIdx.x & 63) == 0) lds[w] = v;
    __syncthreads();
    float r = lds[0] + lds[1];
    __syncthreads();
    return r;
}

// xw = x @ W_gcn (GEMM only; dots moved to k_dots)
__global__ __launch_bounds__(128) void k_gemm(
    const float* __restrict__ x, const float* __restrict__ W,
    float* __restrict__ xw, int n) {
    __shared__ float xs[16][D];
    const int nb = blockIdx.x * 16;
    const int tid = threadIdx.x;
    #pragma unroll
    for (int k = 0; k < 16; k++) {
        int i = nb + k;
        xs[k][tid] = (i < n) ? x[(size_t)i * D + tid] : 0.f;
    }
    __syncthreads();
    float acc[16];
    #pragma unroll
    for (int k = 0; k < 16; k++) acc[k] = 0.f;
    #pragma unroll 4
    for (int d = 0; d < D; d++) {
        float w = W[d * D + tid];
        #pragma unroll
        for (int k = 0; k < 16; k++) acc[k] += xs[k][d] * w;
    }
    #pragma unroll
    for (int k = 0; k < 16; k++) {
        int i = nb + k;
        if (i < n) xw[(size_t)i * D + tid] = acc[k];
    }
}

// per-node scalar dots: xr_rel = x.Wrel, xroot = x.Wroot (1 node per wave)
__global__ __launch_bounds__(256) void k_dots(
    const float* __restrict__ x, const float* __restrict__ Wrel,
    const float* __restrict__ Wroot, float* __restrict__ xr_rel,
    float* __restrict__ xroot, int n) {
    const int lane = threadIdx.x & 63;
    const int i = blockIdx.x * 4 + (threadIdx.x >> 6);
    if (i >= n) return;
    float xa = x[(size_t)i * D + lane];
    float xb = x[(size_t)i * D + 64 + lane];
    float sr = waveReduceSum(xa * Wrel[lane] + xb * Wrel[64 + lane]);
    float so = waveReduceSum(xa * Wroot[lane] + xb * Wroot[64 + lane]);
    if (lane == 0) { xr_rel[i] = sr; xroot[i] = so; }
}

// bucketed adjacency build (store neighbor ids directly) + scalar agg scatter
__global__ void k_edges(const int* __restrict__ ei, int etot, int eorig,
                        int* __restrict__ cnt_col, int* __restrict__ cnt_row,
                        int* __restrict__ lst_col, int* __restrict__ lst_row,
                        float* __restrict__ agg_s,
                        const float* __restrict__ xr_rel) {
    int e = blockIdx.x * blockDim.x + threadIdx.x;
    if (e >= etot) return;
    int r = ei[e];
    int c = ei[etot + e];
    int s1 = atomicAdd(&cnt_col[c], 1);
    if (s1 < CAP) lst_col[(size_t)c * CAP + s1] = r;           // row id
    int s2 = atomicAdd(&cnt_row[r], 1);
    if (s2 < CAP)
        lst_row[(size_t)r * CAP + s2] = c | (e < eorig ? 0x40000000 : 0);
    atomicAdd(&agg_s[c], xr_rel[r]);
}

__global__ void k_dinv(const int* __restrict__ cnt_col,
                       float* __restrict__ dinv, int n) {
    int i = blockIdx.x * blockDim.x + threadIdx.x;
    if (i < n) {
        float d = (float)cnt_col[i];
        dinv[i] = (d > 0.f) ? rsqrtf(d) : 0.f;
    }
}

// x_transform per col-node + fused lk/lq scalars. 4 edge-groups x float4.
__global__ __launch_bounds__(128) void k_xt(
    const float* __restrict__ xw,
    const int* __restrict__ cnt_col, const int* __restrict__ lst_col,
    const float* __restrict__ dinv, const float* __restrict__ b_gcn,
    const float* __restrict__ Wkey, const float* __restrict__ bkey,
    const float* __restrict__ Wq, const float* __restrict__ bq,
    float* __restrict__ xt, float* __restrict__ lk, float* __restrict__ lq,
    int n) {
    const int c = blockIdx.x;
    const int tid = threadIdx.x;
    const int g = tid >> 5;
    const int l = tid & 31;
    __shared__ int rs[CAP];
    __shared__ float ns[CAP];
    __shared__ float part[4][D];
    __shared__ float red[2];
    int deg = min(cnt_col[c], CAP);
    float dc = dinv[c];
    if (tid < deg) {
        int rr = lst_col[(size_t)c * CAP + tid];
        rs[tid] = rr;
        ns[tid] = dinv[rr] * dc;
    }
    __syncthreads();
    float4 acc = make_float4(0.f, 0.f, 0.f, 0.f);
    for (int k = g; k < deg; k += 4) {
        const float4 v = *(const float4*)(xw + (size_t)rs[k] * D + l * 4);
        float w = ns[k];
        acc.x += w * v.x; acc.y += w * v.y;
        acc.z += w * v.z; acc.w += w * v.w;
    }
    *(float4*)(&part[g][l * 4]) = acc;
    __syncthreads();
    float fin = part[0][tid] + part[1][tid] + part[2][tid] + part[3][tid]
                + b_gcn[tid];
    xt[(size_t)c * D + tid] = fin;
    float sk = blockReduceSum128(fin * Wkey[tid], red);
    float sq = blockReduceSum128(fin * Wq[tid], red);
    if (tid == 0) {
        float vk = sk + bkey[0];
        float vq = sq + bq[0];
        lk[c] = vk > 0.f ? vk : NEG * vk;
        lq[c] = vq > 0.f ? vq : NEG * vq;
    }
}

// per row-node: dual softmax + in-register reweight + KE / sum-QE -> score_sum
__global__ __launch_bounds__(128) void k_fused(
    const float* __restrict__ xt,
    const int* __restrict__ cnt_row, const int* __restrict__ lst_row,
    const float* __restrict__ lk, const float* __restrict__ lq,
    float* __restrict__ score_sum, int n) {
    const int r = blockIdx.x;
    const int tid = threadIdx.x;
    const int g = tid >> 5;
    const int l = tid & 31;
    __shared__ int cs[CAP];
    __shared__ unsigned char realf[CAP];
    __shared__ float al[CAP], be[CAP];
    __shared__ float p1[4][D], p2[4][D];
    __shared__ float xrq_row[D];
    __shared__ float red[2];
    __shared__ int nrealsh;
    int deg = min(cnt_row[r], CAP);
    if (tid < deg) {
        int packed = lst_row[(size_t)r * CAP + tid];
        int c = packed & 0x3fffffff;
        cs[tid] = c;
        realf[tid] = (packed >> 30) & 1;
        al[tid] = lk[c];   // raw scores for now
        be[tid] = lq[c];
    }
    __syncthreads();
    if (tid < 64) {  // wave 0: softmax over <=64 edges
        float vk = (tid < deg) ? al[tid] : -3.4e38f;
        float vq = (tid < deg) ? be[tid] : -3.4e38f;
        float mk = waveReduceMax(vk);
        float mq = waveReduceMax(vq);
        float ek = (tid < deg) ? __expf(al[tid] - mk) : 0.f;
        float eq = (tid < deg) ? __expf(be[tid] - mq) : 0.f;
        float zk = waveReduceSum(ek);
        float zq = waveReduceSum(eq);
        if (tid < deg) { al[tid] = ek / zk; be[tid] = eq / zq; }
        int isreal = (tid < deg) ? (int)realf[tid] : 0;
        unsigned long long b = __ballot(isreal);
        if (tid == 0) nrealsh = __popcll(b);
    }
    __syncthreads();
    float4 xrk = make_float4(0.f, 0.f, 0.f, 0.f);
    float4 xrq = make_float4(0.f, 0.f, 0.f, 0.f);
    for (int k = g; k < deg; k += 4) {
        const float4 v = *(const float4*)(xt + (size_t)cs[k] * D + l * 4);
        float a = al[k], b = be[k];
        xrk.x += a * v.x; xrk.y += a * v.y; xrk.z += a * v.z; xrk.w += a * v.w;
        xrq.x += b * v.x; xrq.y += b * v.y; xrq.z += b * v.z; xrq.w += b * v.w;
    }
    *(float4*)(&p1[g][l * 4]) = xrk;
    *(float4*)(&p2[g][l * 4]) = xrq;
    __syncthreads();
    float xrk_c = p1[0][tid] + p1[1][tid] + p1[2][tid] + p1[3][tid];
    float xrq_c = p2[0][tid] + p2[1][tid] + p2[2][tid] + p2[3][tid];
    xrq_row[tid] = xrq_c;
    float xtr = xt[(size_t)r * D + tid];
    float KE = blockReduceSum128(fabsf(xrk_c - xtr), red);  // has syncthreads
    const float4 q4 = *(const float4*)(&xrq_row[l * 4]);
    float sp = 0.f;
    for (int k = g; k < deg; k += 4) {
        if (realf[k]) {
            const float4 v = *(const float4*)(xt + (size_t)cs[k] * D + l * 4);
            sp += fabsf(q4.x - v.x) + fabsf(q4.y - v.y) +
                  fabsf(q4.z - v.z) + fabsf(q4.w - v.w);
        }
    }
    float SQE = blockReduceSum128(sp, red);
    if (tid == 0) score_sum[r] = (float)nrealsh * KE - SQE;
}

__global__ void k_out(const float* __restrict__ agg_s,
                      const float* __restrict__ xroot,
                      const float* __restrict__ brel,
                      const float* __restrict__ score_sum,
                      float* __restrict__ out, int n) {
    int i = blockIdx.x * blockDim.x + threadIdx.x;
    if (i >= n) return;
    float z = agg_s[i] + brel[0] + xroot[i];
    float f = 1.f / (1.f + __expf(-z));
    out[i] = f - LAMB * score_sum[i];
}

extern "C" void kernel_launch(void* const* d_in, const int* in_sizes, int n_in,
                              void* d_out, int out_size, void* d_ws, size_t ws_size,
                              hipStream_t stream) {
    const float* x    = (const float*)d_in[0];
    const int*   ei   = (const int*)d_in[1];
    const float* Wg   = (const float*)d_in[2];
    const float* bg   = (const float*)d_in[3];
    const float* Wk   = (const float*)d_in[4];
    const float* bk   = (const float*)d_in[5];
    const float* Wq   = (const float*)d_in[6];
    const float* bq   = (const float*)d_in[7];
    const float* Wr   = (const float*)d_in[8];
    const float* br   = (const float*)d_in[9];
    const float* Wo   = (const float*)d_in[10];

    const int n = in_sizes[0] / D;        // 50000
    const int etot = in_sizes[1] / 2;     // 850000
    const int eorig = etot - n;           // 800000

    char* ws = (char*)d_ws;
    size_t off = 0;
    auto alloc = [&](size_t bytes) -> void* {
        void* p = ws + off;
        off += (bytes + 255) & ~(size_t)255;
        return p;
    };
    float* xw      = (float*)alloc((size_t)n * D * 4);
    float* xt      = (float*)alloc((size_t)n * D * 4);
    int*   lst_col = (int*)alloc((size_t)n * CAP * 4);
    int*   lst_row = (int*)alloc((size_t)n * CAP * 4);
    int*   cnt_col = (int*)alloc((size_t)n * 4);
    int*   cnt_row = (int*)alloc((size_t)n * 4);
    float* agg_s   = (float*)alloc((size_t)n * 4);
    float* dinv    = (float*)alloc((size_t)n * 4);
    float* lkv     = (float*)alloc((size_t)n * 4);
    float* lqv     = (float*)alloc((size_t)n * 4);
    float* xr_rel  = (float*)alloc((size_t)n * 4);
    float* xroot   = (float*)alloc((size_t)n * 4);
    float* ssum    = (float*)alloc((size_t)n * 4);

    hipMemsetAsync(cnt_col, 0, (size_t)n * 4, stream);
    hipMemsetAsync(cnt_row, 0, (size_t)n * 4, stream);
    hipMemsetAsync(agg_s, 0, (size_t)n * 4, stream);

    k_gemm<<<(n + 15) / 16, 128, 0, stream>>>(x, Wg, xw, n);
    k_dots<<<(n + 3) / 4, 256, 0, stream>>>(x, Wr, Wo, xr_rel, xroot, n);
    k_edges<<<(etot + 255) / 256, 256, 0, stream>>>(ei, etot, eorig,
                                                    cnt_col, cnt_row,
                                                    lst_col, lst_row, agg_s, xr_rel);
    k_dinv<<<(n + 255) / 256, 256, 0, stream>>>(cnt_col, dinv, n);
    k_xt<<<n, 128, 0, stream>>>(xw, cnt_col, lst_col, dinv, bg, Wk, bk,
                                Wq, bq, xt, lkv, lqv, n);
    k_fused<<<n, 128, 0, stream>>>(xt, cnt_row, lst_row, lkv, lqv, ssum, n);
    k_out<<<(n + 255) / 256, 256, 0, stream>>>(agg_s, xroot, br, ssum,
                                               (float*)d_out, n);
}